// Round 5
// baseline (137.438 us; speedup 1.0000x reference)
//
#include <hip/hip_runtime.h>

// B=4096, F0=39, D=16, L=(128,128), H1=64
// Round-5:
//  - Repack with n in LOW thread bits -> fully coalesced f0/f1 reads.
//  - Main: B chunks staged global->LDS once per block (global_load_lds, 2x8KB dbuf),
//    waves read only their col-half frags via conflict-free ds_read_b128.
//    Kills the L1-port duplication (g=0/g=1 read same B) that bounded round 4.
//  - mfma_f32_32x32x16_bf16, M=32 = 2 batches x 16 d, N=128, K=(i,j); A built in regs.
// Layouts (verified):
//  A: lane holds A[m=lane&31][k=(lane>>5)*8+t]
//  B: lane holds B[k=(lane>>5)*8+t][n=lane&31]
//  D: lane holds D[row=(r&3)+8*(r>>2)+4*(lane>>5)][col=lane&31]
// Repacked B layout (BYTES): ch*8192 + kh*4096 + cg*1024 + lane*16 + tp*4
//  L0 ch=ig*5+jg (ig<10,jg<5): i=ig*4+kh*2+half, j=jg*8+t, zero-pad i,j>=39.
//  L1 ch=50+jg*5+ig (jg<16,ig<5): j=jg*4+kh*2+half, i=ig*8+t, zero-pad i>=39.
// Total: 130 chunks * 8192 B = 1,064,960 B of d_ws.

typedef __attribute__((ext_vector_type(8)))  short bf16x8;
typedef __attribute__((ext_vector_type(16))) float f32x16;

static __device__ __forceinline__ unsigned short f2bf_rne(float f) {
    unsigned int u = __builtin_bit_cast(unsigned int, f);
    u = (u + 0x7FFFu + ((u >> 16) & 1u)) >> 16;
    return (unsigned short)u;
}
static __device__ __forceinline__ unsigned int pk_trunc(float a, float b) {
    unsigned int ua = __builtin_bit_cast(unsigned int, a);
    unsigned int ub = __builtin_bit_cast(unsigned int, b);
    return (ua >> 16) | (ub & 0xffff0000u);
}

// ---------------- weight repack: coalesced reads (n = tid&127) ----------------
__global__ __launch_bounds__(256)
void CIN_repack(const float* __restrict__ f0, const float* __restrict__ f1,
                unsigned int* __restrict__ ws)
{
    const int tid  = blockIdx.x * 256 + threadIdx.x;   // 266240 total
    const int n    = tid & 127;
    const int slot = tid >> 7;                          // 0..2079
    const int tp   = slot & 3;
    const int half = (slot >> 2) & 1;
    const int kh   = (slot >> 3) & 1;
    const int ch   = slot >> 4;                         // 0..129
    const int t0   = tp * 2;
    float v0, v1;
    if (ch < 50) {
        const int ig = ch / 5, jg = ch - ig * 5;
        const int i = ig * 4 + kh * 2 + half;           // 0..39
        const int j = jg * 8 + t0;                      // 0..38
        const bool iok = (i < 39);
        v0 = (iok && j     < 39) ? f0[(i * 39 + j    ) * 128 + n] : 0.f;
        v1 = (iok && j + 1 < 39) ? f0[(i * 39 + j + 1) * 128 + n] : 0.f;
    } else {
        const int c1 = ch - 50;
        const int jg = c1 / 5, ig = c1 - jg * 5;
        const int j = jg * 4 + kh * 2 + half;           // 0..63
        const int i = ig * 8 + t0;                      // 0..38
        v0 = (i     < 39) ? f1[( i      * 64 + j) * 128 + n] : 0.f;
        v1 = (i + 1 < 39) ? f1[((i + 1) * 64 + j) * 128 + n] : 0.f;
    }
    const int lane = half * 32 + (n & 31);
    const int cg   = n >> 5;
    const int dst  = ch * 2048 + kh * 1024 + cg * 256 + lane * 4 + tp;
    ws[dst] = (unsigned int)f2bf_rne(v0) | ((unsigned int)f2bf_rne(v1) << 16);
}

// ---------------- main ----------------
static __device__ __forceinline__ bf16x8 build8(float xi, float4 a, float4 b) {
    union { unsigned int u[4]; bf16x8 v; } r;
    r.u[0] = pk_trunc(xi * a.x, xi * a.y);
    r.u[1] = pk_trunc(xi * a.z, xi * a.w);
    r.u[2] = pk_trunc(xi * b.x, xi * b.y);
    r.u[3] = pk_trunc(xi * b.z, xi * b.w);
    return r.v;
}

__global__ __launch_bounds__(256, 2)
void CIN_main(const float* __restrict__ x,
              const char* __restrict__ wsB,
              const float* __restrict__ dw,
              const float* __restrict__ db,
              float* __restrict__ out)
{
    __shared__ __align__(16) unsigned short Bsh[2][4096]; // 2 x 8KB chunk dbuf
    __shared__ __align__(16) float xsTd[8][16][44];       // [bb][d][j], col 39 zeroed
    __shared__ __align__(16) float hsT[8][64][17];        // [bb][j][d]
    __shared__ float dws[192];
    __shared__ float red[2][2][4];

    const int tid  = threadIdx.x;
    const int w    = tid >> 6;
    const int lane = tid & 63;
    const int g    = w & 1;        // batch-group (4 batches)
    const int hh   = w >> 1;       // col-half (n 0..63 / 64..127)
    const int half = lane >> 5;
    const int d    = lane & 15;
    const int bsel = (lane >> 4) & 1;
    const int g4   = g * 4;

    auto stage = [&](int ch) {     // uniform ch; each wave stages its 2KB of the 8KB chunk
        const char* src = wsB + (size_t)ch * 8192 + w * 2048 + lane * 16;
        unsigned short* dst = &Bsh[ch & 1][w * 1024];
        __builtin_amdgcn_global_load_lds(
            (const __attribute__((address_space(1))) void*)src,
            (__attribute__((address_space(3))) void*)dst, 16, 0, 0);
        __builtin_amdgcn_global_load_lds(
            (const __attribute__((address_space(1))) void*)(src + 1024),
            (__attribute__((address_space(3))) void*)(dst + 512), 16, 0, 0);
    };
    auto loadB = [&](int ch, bf16x8 (&B)[2][2]) {
        const char* base = (const char*)&Bsh[ch & 1][0] + lane * 16;
#pragma unroll
        for (int kh = 0; kh < 2; ++kh)
#pragma unroll
            for (int c = 0; c < 2; ++c)
                B[kh][c] = *(const bf16x8*)(base + kh * 4096 + (hh * 2 + c) * 1024);
    };

    stage(0);

    // ---- stage x for 8 batches: 1248 float4, transposed to [d][j] ----
    const float4* xg4 = (const float4*)(x + (size_t)blockIdx.x * 8 * 624);
    for (int e4 = tid; e4 < 1248; e4 += 256) {
        float4 v = xg4[e4];
        int bb = e4 / 156, r = e4 - bb * 156;
        int i = r >> 2, d0 = (r & 3) * 4;
        xsTd[bb][d0 + 0][i] = v.x; xsTd[bb][d0 + 1][i] = v.y;
        xsTd[bb][d0 + 2][i] = v.z; xsTd[bb][d0 + 3][i] = v.w;
    }
    if (tid < 128) { int bb = tid >> 4, dd = tid & 15; xsTd[bb][dd][39] = 0.f; }
    if (tid < 192) dws[tid] = dw[tid];
    __syncthreads();   // covers x staging AND chunk-0 DMA

    // ---- xv: lane's own-batch x row, f32, registers (40 values, idx 39 == 0) ----
    float4 xv[2][10];
#pragma unroll
    for (int p = 0; p < 2; ++p) {
        const float* src = &xsTd[g4 + p * 2 + bsel][d][0];
#pragma unroll
        for (int q = 0; q < 10; ++q) xv[p][q] = *(const float4*)(src + q * 4);
    }

    f32x16 acc[2][2];
#pragma unroll
    for (int p = 0; p < 2; ++p)
#pragma unroll
        for (int c = 0; c < 2; ++c)
#pragma unroll
            for (int r = 0; r < 16; ++r) acc[p][c][r] = 0.f;

    // ---------------- layer 0: 50 chunks ----------------
    for (int ig = 0; ig < 10; ++ig) {
        float xiv[2][2];
#pragma unroll
        for (int p = 0; p < 2; ++p)
#pragma unroll
            for (int kh = 0; kh < 2; ++kh)
                xiv[p][kh] = xsTd[g4 + p * 2 + bsel][d][ig * 4 + kh * 2 + half];
#pragma unroll
        for (int jg = 0; jg < 5; ++jg) {
            const int ch = ig * 5 + jg;
            stage(ch + 1);                 // ch=49 stages chunk 50 (layer-1 chunk 0)
            bf16x8 Bf[2][2];
            loadB(ch, Bf);
            bf16x8 A[2][2];
#pragma unroll
            for (int p = 0; p < 2; ++p)
#pragma unroll
                for (int kh = 0; kh < 2; ++kh)
                    A[p][kh] = build8(xiv[p][kh], xv[p][jg * 2], xv[p][jg * 2 + 1]);
#pragma unroll
            for (int p = 0; p < 2; ++p)
#pragma unroll
                for (int c = 0; c < 2; ++c) {
                    acc[p][c] = __builtin_amdgcn_mfma_f32_32x32x16_bf16(A[p][0], Bf[0][c], acc[p][c], 0, 0, 0);
                    acc[p][c] = __builtin_amdgcn_mfma_f32_32x32x16_bf16(A[p][1], Bf[1][c], acc[p][c], 0, 0, 0);
                }
            __syncthreads();
        }
    }

    // ---------------- layer-0 epilogue ----------------
    float cs[4] = {0.f, 0.f, 0.f, 0.f};
    if (hh == 0) {
#pragma unroll
        for (int p = 0; p < 2; ++p)
#pragma unroll
            for (int c = 0; c < 2; ++c)
#pragma unroll
                for (int r = 0; r < 16; ++r) {
                    const int row = (r & 3) + 8 * (r >> 2) + 4 * half;
                    hsT[g4 + p * 2 + (row >> 4)][c * 32 + (lane & 31)][row & 15] =
                        fmaxf(acc[p][c][r], 0.f);
                }
    } else {
#pragma unroll
        for (int p = 0; p < 2; ++p)
#pragma unroll
            for (int c = 0; c < 2; ++c) {
                const float dwv = dws[c * 32 + (lane & 31)];   // dw[n-64]
#pragma unroll
                for (int r = 0; r < 16; ++r) {
                    const int row = (r & 3) + 8 * (r >> 2) + 4 * half;
                    cs[p * 2 + (row >> 4)] += fmaxf(acc[p][c][r], 0.f) * dwv;
                }
            }
    }
#pragma unroll
    for (int p = 0; p < 2; ++p)
#pragma unroll
        for (int c = 0; c < 2; ++c)
#pragma unroll
            for (int r = 0; r < 16; ++r) acc[p][c][r] = 0.f;
    __syncthreads();   // h visible; chunk-50 DMA already drained at ch=49 barrier

    // ---------------- layer 1: 80 chunks ----------------
    for (int jg = 0; jg < 16; ++jg) {
        float hjv[2][2];
#pragma unroll
        for (int p = 0; p < 2; ++p)
#pragma unroll
            for (int kh = 0; kh < 2; ++kh)
                hjv[p][kh] = hsT[g4 + p * 2 + bsel][jg * 4 + kh * 2 + half][d];
#pragma unroll
        for (int ig2 = 0; ig2 < 5; ++ig2) {
            const int ch = 50 + jg * 5 + ig2;
            if (ch < 129) stage(ch + 1);
            bf16x8 Bf[2][2];
            loadB(ch, Bf);
            bf16x8 A[2][2];
#pragma unroll
            for (int p = 0; p < 2; ++p)
#pragma unroll
                for (int kh = 0; kh < 2; ++kh)
                    A[p][kh] = build8(hjv[p][kh], xv[p][ig2 * 2], xv[p][ig2 * 2 + 1]);
#pragma unroll
            for (int p = 0; p < 2; ++p)
#pragma unroll
                for (int c = 0; c < 2; ++c) {
                    acc[p][c] = __builtin_amdgcn_mfma_f32_32x32x16_bf16(A[p][0], Bf[0][c], acc[p][c], 0, 0, 0);
                    acc[p][c] = __builtin_amdgcn_mfma_f32_32x32x16_bf16(A[p][1], Bf[1][c], acc[p][c], 0, 0, 0);
                }
            __syncthreads();
        }
    }

    // ---------------- layer-1 epilogue + reduction ----------------
#pragma unroll
    for (int p = 0; p < 2; ++p)
#pragma unroll
        for (int c = 0; c < 2; ++c) {
            const float dwv = dws[64 + (2 * hh + c) * 32 + (lane & 31)];
#pragma unroll
            for (int r = 0; r < 16; ++r) {
                const int row = (r & 3) + 8 * (r >> 2) + 4 * half;
                cs[p * 2 + (row >> 4)] += fmaxf(acc[p][c][r], 0.f) * dwv;
            }
        }
#pragma unroll
    for (int rr = 0; rr < 4; ++rr)
#pragma unroll
        for (int off = 32; off > 0; off >>= 1)
            cs[rr] += __shfl_xor(cs[rr], off, 64);
    if (lane == 0) {
#pragma unroll
        for (int rr = 0; rr < 4; ++rr) red[g][hh][rr] = cs[rr];
    }
    __syncthreads();
    if (tid < 8) {
        const int g2 = tid >> 2, rr = tid & 3;
        out[blockIdx.x * 8 + g2 * 4 + rr] = red[g2][0][rr] + red[g2][1][rr] + db[0];
    }
}

extern "C" void kernel_launch(void* const* d_in, const int* in_sizes, int n_in,
                              void* d_out, int out_size, void* d_ws, size_t ws_size,
                              hipStream_t stream)
{
    const float* x  = (const float*)d_in[0];
    const float* f0 = (const float*)d_in[1];
    const float* f1 = (const float*)d_in[2];
    const float* dw = (const float*)d_in[3];
    const float* db = (const float*)d_in[4];
    float* out = (float*)d_out;

    CIN_repack<<<dim3(1040), dim3(256), 0, stream>>>(f0, f1, (unsigned int*)d_ws);
    CIN_main<<<dim3(512), dim3(256), 0, stream>>>(x, (const char*)d_ws, dw, db, out);
}

// Round 6
// 130.641 us; speedup vs baseline: 1.0520x; 1.0520x over previous
//
#include <hip/hip_runtime.h>

// B=4096, F0=39, D=16, L=(128,128), H1=64
// Round-6: round-4 barrier-free B-path (global->VGPR) + copy-free distance-2 prefetch.
//  - mfma_f32_32x32x16_bf16, M=32 = 2 batches x 16 d, N=128, K=(i,j); A built in regs.
//  - Each layer: outer loop x 10 fully-unrolled chunks; 2-phase register B buffer
//    indexed by compile-time (u&1): no Bc=Bn copies, ~8 loads in flight, no K barriers.
//  - xiv/hjv from LDS only at ig/jg boundaries (4 ds_read_b32 per 5 chunks).
// Layouts (verified):
//  A: lane holds A[m=lane&31][k=(lane>>5)*8+t]
//  B: lane holds B[k=(lane>>5)*8+t][n=lane&31]
//  D: lane holds D[row=(r&3)+8*(r>>2)+4*(lane>>5)][col=lane&31]
// Repacked B layout (BYTES): ch*8192 + kh*4096 + cg*1024 + lane*16  (uint4 frag)
//  L0 ch=ig*5+jg (ig<10,jg<5): i=ig*4+kh*2+half, j=jg*8+t, zero-pad i,j>=39.
//  L1 ch=50+jg*5+ig (jg<16,ig<5): j=jg*4+kh*2+half, i=ig*8+t, zero-pad i>=39.
// Total: 130 chunks * 8192 B = 1,064,960 B of d_ws.

typedef __attribute__((ext_vector_type(8)))  short bf16x8;
typedef __attribute__((ext_vector_type(16))) float f32x16;

static __device__ __forceinline__ unsigned short f2bf_rne(float f) {
    unsigned int u = __builtin_bit_cast(unsigned int, f);
    u = (u + 0x7FFFu + ((u >> 16) & 1u)) >> 16;
    return (unsigned short)u;
}
static __device__ __forceinline__ unsigned int pk_trunc(float a, float b) {
    unsigned int ua = __builtin_bit_cast(unsigned int, a);
    unsigned int ub = __builtin_bit_cast(unsigned int, b);
    return (ua >> 16) | (ub & 0xffff0000u);   // v_perm pattern
}

// ---------------- weight repack: coalesced reads, uint4 stores ----------------
__global__ __launch_bounds__(256)
void CIN_repack(const float* __restrict__ f0, const float* __restrict__ f1,
                uint4* __restrict__ ws)
{
    const int tid  = blockIdx.x * 256 + threadIdx.x;   // 66560 total
    const int n    = tid & 127;
    const int slot = tid >> 7;                          // 0..519
    const int half = slot & 1;
    const int kh   = (slot >> 1) & 1;
    const int ch   = slot >> 2;                         // 0..129
    float v[8];
    if (ch < 50) {
        const int ig = ch / 5, jg = ch - ig * 5;
        const int i = ig * 4 + kh * 2 + half;           // 0..39
        const bool iok = (i < 39);
#pragma unroll
        for (int t = 0; t < 8; ++t) {
            const int j = jg * 8 + t;                   // 0..39
            v[t] = (iok && j < 39) ? f0[(i * 39 + j) * 128 + n] : 0.f;
        }
    } else {
        const int c1 = ch - 50;
        const int jg = c1 / 5, ig = c1 - jg * 5;
        const int j = jg * 4 + kh * 2 + half;           // 0..63
#pragma unroll
        for (int t = 0; t < 8; ++t) {
            const int i = ig * 8 + t;                   // 0..39
            v[t] = (i < 39) ? f1[(i * 64 + j) * 128 + n] : 0.f;
        }
    }
    uint4 pk;
    pk.x = (unsigned int)f2bf_rne(v[0]) | ((unsigned int)f2bf_rne(v[1]) << 16);
    pk.y = (unsigned int)f2bf_rne(v[2]) | ((unsigned int)f2bf_rne(v[3]) << 16);
    pk.z = (unsigned int)f2bf_rne(v[4]) | ((unsigned int)f2bf_rne(v[5]) << 16);
    pk.w = (unsigned int)f2bf_rne(v[6]) | ((unsigned int)f2bf_rne(v[7]) << 16);
    const int lane = half * 32 + (n & 31);
    const int cg   = n >> 5;
    ws[ch * 512 + kh * 256 + cg * 64 + lane] = pk;      // uint4 index
}

// ---------------- main ----------------
static __device__ __forceinline__ bf16x8 build8(float xi, float4 a, float4 b) {
    union { unsigned int u[4]; bf16x8 v; } r;
    r.u[0] = pk_trunc(xi * a.x, xi * a.y);
    r.u[1] = pk_trunc(xi * a.z, xi * a.w);
    r.u[2] = pk_trunc(xi * b.x, xi * b.y);
    r.u[3] = pk_trunc(xi * b.z, xi * b.w);
    return r.v;
}

__global__ __launch_bounds__(256, 2)
void CIN_main(const float* __restrict__ x,
              const char* __restrict__ wsB,
              const float* __restrict__ dw,
              const float* __restrict__ db,
              float* __restrict__ out)
{
    __shared__ __align__(16) float xsTd[8][16][44];       // [bb][d][j], col 39 zeroed
    __shared__ __align__(16) float hsT[8][64][17];        // [bb][j][d]
    __shared__ float dws[192];
    __shared__ float red[2][2][4];

    const int tid  = threadIdx.x;
    const int w    = tid >> 6;
    const int lane = tid & 63;
    const int g    = w & 1;        // batch-group (4 batches)
    const int hh   = w >> 1;       // col-half (n 0..63 / 64..127)
    const int half = lane >> 5;
    const int d    = lane & 15;
    const int bsel = (lane >> 4) & 1;
    const int g4   = g * 4;

    // B frag base: rebase +2560 so all 4 offsets {-2560,-1536,+1536,+2560} fit imm13
    const char* wbase = wsB + lane * 16 + hh * 2048 + 2560;
    bf16x8 Bb[2][2][2];            // [phase][kh][c]
    auto loadBg = [&](int ch, bf16x8 (&B)[2][2]) {
        const char* p0 = wbase + (size_t)ch * 8192;
        B[0][0] = *(const bf16x8*)(p0 - 2560);
        B[0][1] = *(const bf16x8*)(p0 - 1536);
        B[1][0] = *(const bf16x8*)(p0 + 1536);
        B[1][1] = *(const bf16x8*)(p0 + 2560);
    };

    loadBg(0, Bb[0]);              // issued before x staging: latency fully hidden
    loadBg(1, Bb[1]);

    // ---- stage x for 8 batches: 1248 float4, transposed to [d][j] ----
    const float4* xg4 = (const float4*)(x + (size_t)blockIdx.x * 8 * 624);
    for (int e4 = tid; e4 < 1248; e4 += 256) {
        float4 v = xg4[e4];
        int bb = e4 / 156, r = e4 - bb * 156;
        int i = r >> 2, d0 = (r & 3) * 4;
        xsTd[bb][d0 + 0][i] = v.x; xsTd[bb][d0 + 1][i] = v.y;
        xsTd[bb][d0 + 2][i] = v.z; xsTd[bb][d0 + 3][i] = v.w;
    }
    if (tid < 128) { int bb = tid >> 4, dd = tid & 15; xsTd[bb][dd][39] = 0.f; }
    if (tid < 192) dws[tid] = dw[tid];
    __syncthreads();

    // ---- xv: lane's own-batch x row, f32, registers (40 values, idx 39 == 0) ----
    float4 xv[2][10];
#pragma unroll
    for (int p = 0; p < 2; ++p) {
        const float* src = &xsTd[g4 + p * 2 + bsel][d][0];
#pragma unroll
        for (int q = 0; q < 10; ++q) xv[p][q] = *(const float4*)(src + q * 4);
    }

    f32x16 acc[2][2];
#pragma unroll
    for (int p = 0; p < 2; ++p)
#pragma unroll
        for (int c = 0; c < 2; ++c)
#pragma unroll
            for (int r = 0; r < 16; ++r) acc[p][c][r] = 0.f;

    float xiv[2][2];

    // ---------------- layer 0: 5 outer x 10 unrolled chunks ----------------
#pragma unroll 1
    for (int o = 0; o < 5; ++o) {
#pragma unroll
        for (int u = 0; u < 10; ++u) {
            const int ch = o * 10 + u;
            const int jg = u % 5;
            if (jg == 0) {
                const int ib = (o * 2 + u / 5) * 4;
#pragma unroll
                for (int p = 0; p < 2; ++p)
#pragma unroll
                    for (int kh = 0; kh < 2; ++kh)
                        xiv[p][kh] = xsTd[g4 + p * 2 + bsel][d][ib + kh * 2 + half];
            }
            bf16x8 A[2][2];
#pragma unroll
            for (int p = 0; p < 2; ++p)
#pragma unroll
                for (int kh = 0; kh < 2; ++kh)
                    A[p][kh] = build8(xiv[p][kh], xv[p][jg * 2], xv[p][jg * 2 + 1]);
#pragma unroll
            for (int p = 0; p < 2; ++p)
#pragma unroll
                for (int c = 0; c < 2; ++c) {
                    acc[p][c] = __builtin_amdgcn_mfma_f32_32x32x16_bf16(A[p][0], Bb[u & 1][0][c], acc[p][c], 0, 0, 0);
                    acc[p][c] = __builtin_amdgcn_mfma_f32_32x32x16_bf16(A[p][1], Bb[u & 1][1][c], acc[p][c], 0, 0, 0);
                }
            loadBg(ch + 2, Bb[u & 1]);   // max ch+2 = 51 (layer-1 chunks 50/51) — in bounds
        }
    }

    // ---------------- layer-0 epilogue ----------------
    float cs[4] = {0.f, 0.f, 0.f, 0.f};
    if (hh == 0) {
#pragma unroll
        for (int p = 0; p < 2; ++p)
#pragma unroll
            for (int c = 0; c < 2; ++c)
#pragma unroll
                for (int r = 0; r < 16; ++r) {
                    const int row = (r & 3) + 8 * (r >> 2) + 4 * half;
                    hsT[g4 + p * 2 + (row >> 4)][c * 32 + (lane & 31)][row & 15] =
                        fmaxf(acc[p][c][r], 0.f);
                }
    } else {
#pragma unroll
        for (int p = 0; p < 2; ++p)
#pragma unroll
            for (int c = 0; c < 2; ++c) {
                const float dwv = dws[c * 32 + (lane & 31)];   // dw[n-64]
#pragma unroll
                for (int r = 0; r < 16; ++r) {
                    const int row = (r & 3) + 8 * (r >> 2) + 4 * half;
                    cs[p * 2 + (row >> 4)] += fmaxf(acc[p][c][r], 0.f) * dwv;
                }
            }
    }
#pragma unroll
    for (int p = 0; p < 2; ++p)
#pragma unroll
        for (int c = 0; c < 2; ++c)
#pragma unroll
            for (int r = 0; r < 16; ++r) acc[p][c][r] = 0.f;
    __syncthreads();   // h visible to both col-half wave pairs

    // ---------------- layer 1: 8 outer x 10 unrolled chunks (50..129) ----------------
    // phase continuity: chunk 50 -> u=0 -> Bb[0] (prefetched at o=4,u=8) OK
#pragma unroll 1
    for (int o2 = 0; o2 < 8; ++o2) {
#pragma unroll
        for (int u = 0; u < 10; ++u) {
            const int ch = 50 + o2 * 10 + u;
            const int ig2 = u % 5;
            if (ig2 == 0) {
                const int jb = (o2 * 2 + u / 5) * 4;
#pragma unroll
                for (int p = 0; p < 2; ++p)
#pragma unroll
                    for (int kh = 0; kh < 2; ++kh)
                        xiv[p][kh] = hsT[g4 + p * 2 + bsel][jb + kh * 2 + half][d];
            }
            bf16x8 A[2][2];
#pragma unroll
            for (int p = 0; p < 2; ++p)
#pragma unroll
                for (int kh = 0; kh < 2; ++kh)
                    A[p][kh] = build8(xiv[p][kh], xv[p][ig2 * 2], xv[p][ig2 * 2 + 1]);
#pragma unroll
            for (int p = 0; p < 2; ++p)
#pragma unroll
                for (int c = 0; c < 2; ++c) {
                    acc[p][c] = __builtin_amdgcn_mfma_f32_32x32x16_bf16(A[p][0], Bb[u & 1][0][c], acc[p][c], 0, 0, 0);
                    acc[p][c] = __builtin_amdgcn_mfma_f32_32x32x16_bf16(A[p][1], Bb[u & 1][1][c], acc[p][c], 0, 0, 0);
                }
            int chn = ch + 2; if (chn > 129) chn = 129;   // scalar clamp, stays in bounds
            loadBg(chn, Bb[u & 1]);
        }
    }

    // ---------------- layer-1 epilogue + reduction ----------------
#pragma unroll
    for (int p = 0; p < 2; ++p)
#pragma unroll
        for (int c = 0; c < 2; ++c) {
            const float dwv = dws[64 + (2 * hh + c) * 32 + (lane & 31)];
#pragma unroll
            for (int r = 0; r < 16; ++r) {
                const int row = (r & 3) + 8 * (r >> 2) + 4 * half;
                cs[p * 2 + (row >> 4)] += fmaxf(acc[p][c][r], 0.f) * dwv;
            }
        }
#pragma unroll
    for (int rr = 0; rr < 4; ++rr)
#pragma unroll
        for (int off = 32; off > 0; off >>= 1)
            cs[rr] += __shfl_xor(cs[rr], off, 64);
    if (lane == 0) {
#pragma unroll
        for (int rr = 0; rr < 4; ++rr) red[g][hh][rr] = cs[rr];
    }
    __syncthreads();
    if (tid < 8) {
        const int g2 = tid >> 2, rr = tid & 3;
        out[blockIdx.x * 8 + g2 * 4 + rr] = red[g2][0][rr] + red[g2][1][rr] + db[0];
    }
}

extern "C" void kernel_launch(void* const* d_in, const int* in_sizes, int n_in,
                              void* d_out, int out_size, void* d_ws, size_t ws_size,
                              hipStream_t stream)
{
    const float* x  = (const float*)d_in[0];
    const float* f0 = (const float*)d_in[1];
    const float* f1 = (const float*)d_in[2];
    const float* dw = (const float*)d_in[3];
    const float* db = (const float*)d_in[4];
    float* out = (float*)d_out;

    CIN_repack<<<dim3(260), dim3(256), 0, stream>>>(f0, f1, (uint4*)d_ws);
    CIN_main<<<dim3(512), dim3(256), 0, stream>>>(x, (const char*)d_ws, dw, db, out);
}